// Round 13
// baseline (223.958 us; speedup 1.0000x reference)
//
#include <hip/hip_runtime.h>
#include <hip/hip_bf16.h>

typedef __attribute__((ext_vector_type(8))) short short8;
typedef __attribute__((ext_vector_type(4))) float f32x4;
typedef __attribute__((ext_vector_type(16))) float f32x16;

#define MFMA16(a,b,c) __builtin_amdgcn_mfma_f32_16x16x32_bf16((a),(b),(c),0,0,0)
#define MFMA32(a,b,c) __builtin_amdgcn_mfma_f32_32x32x16_bf16((a),(b),(c),0,0,0)

static __device__ __forceinline__ float b2f(ushort u){
  union { unsigned u32; float f; } x; x.u32 = ((unsigned)u) << 16; return x.f;
}
// packed f32->bf16 (RNE), 1 VALU for 2 values
static __device__ __forceinline__ unsigned cvt2(float lo, float hi){
  unsigned r; asm("v_cvt_pk_bf16_f32 %0, %1, %2" : "=v"(r) : "v"(lo), "v"(hi)); return r;
}
static __device__ __forceinline__ ushort f2b1(float f){
  unsigned r; asm("v_cvt_pk_bf16_f32 %0, %1, %2" : "=v"(r) : "v"(f), "v"(f));
  return (ushort)r;
}
// NaN-PROPAGATING relu (fmaxf(NaN,0)==0 would mask upstream NaNs)
static __device__ __forceinline__ float relu(float v){ return (v <= 0.f) ? 0.f : v; }

// ---------------- K1: prep panels + in-block kNN + sparse interp (1024 blocks)
// blocks [0,512): spw->bf16 panel [kblk 128][o 512][8]
// blocks [512,768): A panels [kblk 64][o 128][8]; blk 512 also zeroes BN stats
// blocks [768,1024): per-b kNN (recomputed in-block) + spiT panel
__global__ __launch_bounds__(256) void k_prep(
    const float* __restrict__ spw, ushort* __restrict__ spwb,
    const float* __restrict__ ctw, ushort* __restrict__ Aev, ushort* __restrict__ Aod,
    const float* __restrict__ sf, const float* __restrict__ bef,
    const float* __restrict__ coor, int* __restrict__ idx, float* __restrict__ wgt,
    ushort* __restrict__ spiT, float* __restrict__ stats){
  __shared__ float Ls[128*33];
  __shared__ float kw0[64], kw1[64];
  __shared__ int   ki0[64], ki1[64];
  int blk = blockIdx.x, tid = threadIdx.x;
  if(blk < 512){
    int i = blk*256 + tid;                  // float4 index, 131072 total
    int o = i >> 8;                         // sp_w is [512 o][1024 k]
    int k = (i & 255) * 4;
    f32x4 v = *((const f32x4*)spw + i);
    uint2 ov; ov.x = cvt2(v.x, v.y); ov.y = cvt2(v.z, v.w);
    *(uint2*)(spwb + (size_t)(k>>3)*4096 + o*8 + (k&7)) = ov;
  } else if(blk < 768){
    if(blk == 512){   // zero BN accumulators (sstats 1024 + dstats 256) every launch
      for(int j = tid; j < 1280; j += 256) stats[j] = 0.f;
    }
    int i = (blk-512)*256 + tid;            // 65536 = o*512 + kc
    int o = i >> 9, kc = i & 511;
    int c = kc & 255, hi = kc >> 8;
    const float* w = ctw + ((size_t)c*128 + o)*4;   // [in 256][out 128][1][4]
    int j = ((kc>>3)<<10) + (o<<3) + (kc&7);
    Aev[j] = f2b1(w[hi ? 3 : 1]);           // A_even = [kw1 ; kw3]
    Aod[j] = f2b1(w[hi ? 2 : 0]);           // A_odd  = [kw0 ; kw2]
  } else {
    int blk2 = blk - 768;                   // 256 blocks: b(32) x cchunk(8)
    int b = blk2 >> 3, c0 = (blk2 & 7) * 128;
    const float* src = sf + (size_t)b*32768 + (size_t)c0*32;   // [c][32 m]
    #pragma unroll
    for(int it=0; it<4; ++it){
      int q = it*256 + tid;        // float4 id, 1024 total
      int c = q >> 3, m = (q & 7)*4;
      f32x4 v = *(const f32x4*)(src + c*32 + m);
      Ls[c*33+m] = v.x; Ls[c*33+m+1] = v.y; Ls[c*33+m+2] = v.z; Ls[c*33+m+3] = v.w;
    }
    // in-block kNN for this b (every spiT block recomputes; tiny, L2-cached)
    {
      int n = tid & 63;
      int t = b*64 + n;
      float v[32]; float sb = 0.f;
      const float* br = bef + (size_t)t * 32;
      #pragma unroll
      for(int c=0;c<32;c++){ float x = br[c]; v[c] = x; sb += x*x; }
      float d0 = 1e30f, d1 = 1e30f; int i0 = 0, i1 = 0;
      const float* cr = coor + (size_t)b * 1024;
      for(int m=0;m<32;m++){
        float dot = 0.f, sc = 0.f;
        #pragma unroll
        for(int c=0;c<32;c++){ float x = cr[m*32+c]; dot += v[c]*x; sc += x*x; }
        float d = sb + sc - 2.f*dot;
        if(d < d0){ d1 = d0; i1 = i0; d0 = d; i0 = m; }   // strict < keeps lowest idx on ties
        else if(d < d1){ d1 = d; i1 = m; }
      }
      float r0 = 1.f/(d0 + 1e-8f), r1 = 1.f/(d1 + 1e-8f);
      float sum = r0 + r1;
      if(tid < 64){
        ki0[n] = i0; ki1[n] = i1;
        kw0[n] = r0/sum; kw1[n] = r1/sum;
        if(c0 == 0){   // publish for k_mid / k_dout
          idx[t*2] = i0; idx[t*2+1] = i1;
          wgt[t*2] = r0/sum; wgt[t*2+1] = r1/sum;
        }
      }
    }
    __syncthreads();
    int n = tid & 63, ob = tid >> 6;
    int i0 = ki0[n], i1 = ki1[n];
    float w0 = kw0[n], w1 = kw1[n];
    ushort* dst = spiT + (size_t)b*65536 + n*8;
    #pragma unroll
    for(int it=0; it<4; ++it){
      int oct = ob + it*4;                 // 0..15 (8 c's each)
      float f[8];
      #pragma unroll
      for(int j=0;j<8;j++){
        int c = oct*8 + j;
        f[j] = w0*Ls[c*33+i0] + w1*Ls[c*33+i1];
      }
      uint4 uv; uv.x = cvt2(f[0],f[1]); uv.y = cvt2(f[2],f[3]);
      uv.z = cvt2(f[4],f[5]); uv.w = cvt2(f[6],f[7]);
      *(uint4*)(dst + (size_t)((c0>>3) + oct)*512) = uv;   // 64-lane contiguous 1KB store
    }
  }
}

// ---------------- K2: sgemm (blocks 0..511) || conv (blocks 512..1535) --------
__global__ __launch_bounds__(256) void k_main(
    const ushort* __restrict__ spw, const ushort* __restrict__ spiT,
    const float* __restrict__ spb, float* __restrict__ h, float* __restrict__ sstats,
    const float* __restrict__ df, const ushort* __restrict__ Aev,
    const ushort* __restrict__ Aod, const float* __restrict__ ctb,
    ushort* __restrict__ z){
  __shared__ ushort L[66*256];   // 33792 B (conv path only)
  int tid = threadIdx.x;
  int wave = tid >> 6, lane = tid & 63;

  if(blockIdx.x < 512){
    // ================= sgemm =================
    int blk = blockIdx.x;
    int b = blk >> 4, og = (blk >> 1) & 7, nh = blk & 1;
    int lo = lane & 15, hi = lane >> 4;
    int o0 = og*64 + wave*16;
    const short* A = (const short*)spw  + (size_t)hi*4096 + (o0 + lo)*8;
    const short* B = (const short*)spiT + (size_t)b*65536 + (size_t)hi*512 + (nh*32 + lo)*8;
    f32x4 acc[2] = {};
    for(int kb = 0; kb < 128; kb += 4){
      short8 a = *(const short8*)(A + (size_t)kb*4096);
      acc[0] = MFMA16(a, *(const short8*)(B + (size_t)kb*512),       acc[0]);
      acc[1] = MFMA16(a, *(const short8*)(B + (size_t)kb*512 + 128), acc[1]);
    }
    float sv[4], sv2[4], bias[4];
    #pragma unroll
    for(int r=0;r<4;r++){ sv[r]=0.f; sv2[r]=0.f; bias[r] = spb[o0 + hi*4 + r]; }
    #pragma unroll
    for(int q=0;q<2;q++){
      int n = nh*32 + q*16 + lo;
      #pragma unroll
      for(int r=0;r<4;r++){
        int o = o0 + hi*4 + r;
        float val = acc[q][r] + bias[r];
        h[(size_t)o*2048 + b*64 + n] = val;
        sv[r] += val; sv2[r] += val*val;
      }
    }
    #pragma unroll
    for(int r=0;r<4;r++){
      #pragma unroll
      for(int off=1; off<16; off<<=1){
        sv[r]  += __shfl_xor(sv[r],  off);
        sv2[r] += __shfl_xor(sv2[r], off);
      }
    }
    if(lo == 0){
      #pragma unroll
      for(int r=0;r<4;r++){
        int o = o0 + hi*4 + r;
        atomicAdd(&sstats[o*2],   sv[r]);
        atomicAdd(&sstats[o*2+1], sv2[r]);
      }
    }
    return;
  }

  // ================= conv =================
  int bs_ = blockIdx.x - 512; int b = bs_ >> 5, s = bs_ & 31;
  { // zero boundary rows 0 and 65
    unsigned* Lw = (unsigned*)L;
    int i = (tid < 128) ? tid : (65*128 + (tid - 128));
    Lw[i] = 0u;
  }
  // stage + transpose + f32->bf16: thread = p (64 lanes), c-oct; 8 iters.
  {
    int p = tid & 63;
    const float* src = df + ((size_t)(b*256)*32 + s)*64 + p;   // + c*2048
    int row = p + 1;
    char* Lrow = (char*)L + row*512;
    int rsw = row & 31;
    #pragma unroll
    for(int it=0; it<8; ++it){
      int oct = (tid >> 6) + it*4;        // 0..31
      const float* sc = src + (size_t)oct*8*2048;
      float f[8];
      #pragma unroll
      for(int j=0;j<8;j++) f[j] = sc[(size_t)j*2048];
      uint4 uv; uv.x = cvt2(f[0],f[1]); uv.y = cvt2(f[2],f[3]);
      uv.z = cvt2(f[4],f[5]); uv.w = cvt2(f[6],f[7]);
      *(uint4*)(Lrow + ((oct ^ rsw) << 4)) = uv;
    }
  }
  __syncthreads();

  int pe = wave >> 1, tt = wave & 1;     // parity, t-tile
  int tcol = lane & 31;
  int t = tt*32 + tcol;
  int kl = (lane >> 5) * 8;              // k sub-group for LDS B-frag
  const short* A = (const short*)(pe ? Aod : Aev) + (size_t)(lane>>5)*1024 + tcol*8;
  f32x16 acc[4] = {};
  #pragma unroll
  for(int hf=0; hf<2; ++hf){
    int rowr = t + (hf==0 ? 1 : 0) + pe;       // source L-row for this parity/half
    const char* Lr = (const char*)L + rowr*512;
    int rsw = rowr & 31;
    for(int k0=0; k0<256; k0+=16){
      int sidx = (k0 + kl) >> 3;               // LDS slot (column oct)
      short8 bfrag = *(const short8*)(Lr + ((sidx ^ rsw) << 4));
      const short* Ab = A + (size_t)((hf*256 + k0) >> 3)*1024;
      #pragma unroll
      for(int ot=0; ot<4; ++ot){
        short8 afrag = *(const short8*)(Ab + ot*256);   // 2x512B contiguous segments
        acc[ot] = MFMA32(afrag, bfrag, acc[ot]);
      }
    }
  }
  __syncthreads();   // all waves done reading L before repack overwrite

  // repack via LDS: Z[o 128][wo 128] bf16 (32 KB, reuse L)
  #pragma unroll
  for(int ot=0; ot<4; ++ot){
    #pragma unroll
    for(int r=0;r<16;r++){
      int o = ot*32 + (r&3) + 8*(r>>2) + 4*(lane>>5);
      L[o*128 + 2*t + pe] = f2b1(acc[ot][r] + ctb[o]);
    }
  }
  __syncthreads();
  // linear coalesced store: z[b][o][s][wo]
  ushort* zb = z + ((size_t)(b*128)*32 + s)*128;
  #pragma unroll
  for(int it=0; it<8; ++it){
    int q = it*256 + tid;          // short8 chunk, 2048 total
    int o = q >> 4, w0 = (q & 15)*8;
    *(short8*)(zb + (size_t)o*4096 + w0) = *(const short8*)(L + o*128 + w0);
  }
}

// ---------------- K3: merged sparse-BN normalize + dense-BN stats -------------
// blocks [0,512): sbn (o = blk); blocks [512, 4608): dstats task = blk-512
__global__ __launch_bounds__(256) void k_mid(const float* __restrict__ h,
    const float* __restrict__ sstats, const float* __restrict__ gam,
    const float* __restrict__ bet, float* __restrict__ out,
    const ushort* __restrict__ z, const int* __restrict__ idx,
    const float* __restrict__ wgt, float* __restrict__ dstats){
  __shared__ float ps[4], ps2[4];
  __shared__ uint4 Lz[512];              // 8 KB z slab
  int blk = blockIdx.x, tid = threadIdx.x;
  if(blk < 512){
    int o = blk;
    float mu = sstats[o*2] / 2048.f;
    float var = fmaxf(sstats[o*2+1] / 2048.f - mu*mu, 0.f);
    float a = gam[o] * rsqrtf(var + 1e-5f);
    float be = bet[o];
    const float* row = h + (size_t)o * 2048;
    #pragma unroll
    for(int it=0; it<2; ++it){
      int j = it*1024 + tid*4;
      f32x4 v = *(const f32x4*)(row + j);
      f32x4 r;
      r.x = relu(a*(v.x-mu)+be); r.y = relu(a*(v.y-mu)+be);
      r.z = relu(a*(v.z-mu)+be); r.w = relu(a*(v.w-mu)+be);
      int b = j >> 6, n = j & 63;
      *(f32x4*)(out + ((size_t)b*512 + o)*64 + n) = r;
    }
  } else {
    int t = blk - 512; int b = t >> 7, o = t & 127;
    const uint4* zq = (const uint4*)(z + (size_t)(b*128 + o) * 4096);  // [32 s][16 chunks]
    Lz[tid]       = zq[tid];
    Lz[tid + 256] = zq[tid + 256];
    __syncthreads();
    int wq = tid & 15, ng = tid >> 4;       // 16 chunks x 16 n-groups
    float s = 0.f, s2 = 0.f;
    for(int n = ng; n < 64; n += 16){
      int bn = b*64 + n;
      float w0 = wgt[bn*2], w1 = wgt[bn*2+1];
      int i0 = idx[bn*2], i1 = idx[bn*2+1];
      uint4 a0 = Lz[i0*16 + wq], a1 = Lz[i1*16 + wq];
      #pragma unroll
      for(int j=0;j<4;j++){
        unsigned u0 = (&a0.x)[j], u1 = (&a1.x)[j];
        float y0 = w0*b2f((ushort)u0)       + w1*b2f((ushort)u1);
        float y1 = w0*b2f((ushort)(u0>>16)) + w1*b2f((ushort)(u1>>16));
        s += y0 + y1; s2 += y0*y0 + y1*y1;
      }
    }
    #pragma unroll
    for(int off=32; off; off>>=1){ s += __shfl_down(s, off); s2 += __shfl_down(s2, off); }
    int wave = tid >> 6, lane = tid & 63;
    if(lane == 0){ ps[wave] = s; ps2[wave] = s2; }
    __syncthreads();
    if(tid == 0){
      atomicAdd(&dstats[o*2],   ps[0]+ps[1]+ps[2]+ps[3]);
      atomicAdd(&dstats[o*2+1], ps2[0]+ps2[1]+ps2[2]+ps2[3]);
    }
  }
}

// ---------------- K4: dense normalize + ReLU -> d_out (LDS-staged gather) -----
__global__ __launch_bounds__(256) void k_dout(const ushort* __restrict__ z,
    const int* __restrict__ idx, const float* __restrict__ wgt,
    const float* __restrict__ stats, const float* __restrict__ gam,
    const float* __restrict__ bet, float* __restrict__ out){
  __shared__ uint4 Lz[512];              // 8 KB z slab
  int blk = blockIdx.x; int b = blk >> 7, o = blk & 127;
  const float N = 262144.f;
  float mu = stats[o*2] / N;
  float var = fmaxf(stats[o*2+1] / N - mu*mu, 0.f);
  float a = gam[o] * rsqrtf(var + 1e-5f);
  float be = bet[o];
  int tid = threadIdx.x;
  const uint4* zq = (const uint4*)(z + (size_t)(b*128 + o) * 4096);
  Lz[tid]       = zq[tid];
  Lz[tid + 256] = zq[tid + 256];
  __syncthreads();
  float* ob = out + 1048576 + (size_t)(b*128 + o) * 8192;   // [n 64][wo 128]
  int wq = tid & 15, ng = tid >> 4;
  for(int n = ng; n < 64; n += 16){
    int bn = b*64 + n;
    float w0 = wgt[bn*2], w1 = wgt[bn*2+1];
    int i0 = idx[bn*2], i1 = idx[bn*2+1];
    uint4 a0 = Lz[i0*16 + wq], a1 = Lz[i1*16 + wq];
    float y[8];
    #pragma unroll
    for(int j=0;j<4;j++){
      unsigned u0 = (&a0.x)[j], u1 = (&a1.x)[j];
      y[2*j]   = w0*b2f((ushort)u0)       + w1*b2f((ushort)u1);
      y[2*j+1] = w0*b2f((ushort)(u0>>16)) + w1*b2f((ushort)(u1>>16));
    }
    f32x4 r0, r1;
    r0.x = relu(a*(y[0]-mu)+be); r0.y = relu(a*(y[1]-mu)+be);
    r0.z = relu(a*(y[2]-mu)+be); r0.w = relu(a*(y[3]-mu)+be);
    r1.x = relu(a*(y[4]-mu)+be); r1.y = relu(a*(y[5]-mu)+be);
    r1.z = relu(a*(y[6]-mu)+be); r1.w = relu(a*(y[7]-mu)+be);
    *(f32x4*)(ob + n*128 + wq*8)     = r0;
    *(f32x4*)(ob + n*128 + wq*8 + 4) = r1;
  }
}

extern "C" void kernel_launch(void* const* d_in, const int* in_sizes, int n_in,
                              void* d_out, int out_size, void* d_ws, size_t ws_size,
                              hipStream_t stream) {
  (void)in_sizes; (void)n_in; (void)out_size; (void)ws_size;
  const float* sparse_fea = (const float*)d_in[0];
  const float* dense_fea  = (const float*)d_in[1];
  const float* stk_coor   = (const float*)d_in[2];
  const float* stk_bef    = (const float*)d_in[3];
  const float* sp_w   = (const float*)d_in[4];
  const float* sp_b   = (const float*)d_in[5];
  const float* sp_g   = (const float*)d_in[6];
  const float* sp_be  = (const float*)d_in[7];
  const float* ct_w   = (const float*)d_in[8];
  const float* ct_b   = (const float*)d_in[9];
  const float* bn_g   = (const float*)d_in[10];
  const float* bn_be  = (const float*)d_in[11];
  float* out = (float*)d_out;

  char* ws = (char*)d_ws;
  int*    idx    = (int*)   (ws + 0);          //  16 KB
  float*  wgt    = (float*) (ws + 16384);      //  16 KB
  float*  sstats = (float*) (ws + 32768);      //   4 KB (512 o x {sum,sumsq})
  float*  dstats = (float*) (ws + 36864);      //   1 KB (contiguous after sstats)
  ushort* Aev    = (ushort*)(ws + 40960);      // 128 KB (panel)
  ushort* Aod    = (ushort*)(ws + 172032);     // 128 KB (panel)
  ushort* spwb   = (ushort*)(ws + 303104);     //   1 MB (sp_w bf16 panel)
  ushort* spiT   = (ushort*)(ws + 1351680);    //   4 MB (panel)
  float*  h      = (float*) (ws + 5545984);    //   4 MB
  ushort* z      = (ushort*)(ws + 9740288);    //  32 MB

  // ===== ATTRIBUTION ROUND: front half duplicated (prep,main)x2 =====
  // Correctness-preserving: k_prep is idempotent and re-zeroes the stat
  // accumulators (block 512), so the second k_main re-accumulates sstats
  // from zero and rewrites h/z identically. dur_us - 137 ~= t(prep)+t(main).
  hipLaunchKernelGGL(k_prep, dim3(1024), dim3(256), 0, stream,
                     sp_w, spwb, ct_w, Aev, Aod, sparse_fea, stk_bef, stk_coor,
                     idx, wgt, spiT, sstats);
  hipLaunchKernelGGL(k_main, dim3(1536), dim3(256), 0, stream,
                     spwb, spiT, sp_b, h, sstats, dense_fea, Aev, Aod, ct_b, z);
  hipLaunchKernelGGL(k_prep, dim3(1024), dim3(256), 0, stream,
                     sp_w, spwb, ct_w, Aev, Aod, sparse_fea, stk_bef, stk_coor,
                     idx, wgt, spiT, sstats);
  hipLaunchKernelGGL(k_main, dim3(1536), dim3(256), 0, stream,
                     spwb, spiT, sp_b, h, sstats, dense_fea, Aev, Aod, ct_b, z);
  hipLaunchKernelGGL(k_mid,  dim3(4608), dim3(256), 0, stream,
                     h, sstats, sp_g, sp_be, out, z, idx, wgt, dstats);
  hipLaunchKernelGGL(k_dout, dim3(4096), dim3(256), 0, stream,
                     z, idx, wgt, dstats, bn_g, bn_be, out);
}

// Round 14
// 164.954 us; speedup vs baseline: 1.3577x; 1.3577x over previous
//
#include <hip/hip_runtime.h>
#include <hip/hip_bf16.h>

typedef __attribute__((ext_vector_type(8))) short short8;
typedef __attribute__((ext_vector_type(4))) float f32x4;
typedef __attribute__((ext_vector_type(16))) float f32x16;

#define MFMA16(a,b,c) __builtin_amdgcn_mfma_f32_16x16x32_bf16((a),(b),(c),0,0,0)
#define MFMA32(a,b,c) __builtin_amdgcn_mfma_f32_32x32x16_bf16((a),(b),(c),0,0,0)

static __device__ __forceinline__ float b2f(ushort u){
  union { unsigned u32; float f; } x; x.u32 = ((unsigned)u) << 16; return x.f;
}
// packed f32->bf16 (RNE), 1 VALU for 2 values
static __device__ __forceinline__ unsigned cvt2(float lo, float hi){
  unsigned r; asm("v_cvt_pk_bf16_f32 %0, %1, %2" : "=v"(r) : "v"(lo), "v"(hi)); return r;
}
static __device__ __forceinline__ ushort f2b1(float f){
  unsigned r; asm("v_cvt_pk_bf16_f32 %0, %1, %2" : "=v"(r) : "v"(f), "v"(f));
  return (ushort)r;
}
// NaN-PROPAGATING relu (fmaxf(NaN,0)==0 would mask upstream NaNs)
static __device__ __forceinline__ float relu(float v){ return (v <= 0.f) ? 0.f : v; }

// ---------------- K1: prep panels + in-block kNN + sparse interp (1024 blocks)
// blocks [0,512): spw->bf16 panel [kblk 128][o 512][8]
// blocks [512,768): A panels [kblk 64][o 128][8]; blk 512 also zeroes BN stats
// blocks [768,1024): per-b kNN (recomputed in-block) + spiT panel
__global__ __launch_bounds__(256) void k_prep(
    const float* __restrict__ spw, ushort* __restrict__ spwb,
    const float* __restrict__ ctw, ushort* __restrict__ Aev, ushort* __restrict__ Aod,
    const float* __restrict__ sf, const float* __restrict__ bef,
    const float* __restrict__ coor, int* __restrict__ idx, float* __restrict__ wgt,
    ushort* __restrict__ spiT, float* __restrict__ stats){
  __shared__ float Ls[128*33];
  __shared__ float kw0[64], kw1[64];
  __shared__ int   ki0[64], ki1[64];
  int blk = blockIdx.x, tid = threadIdx.x;
  if(blk < 512){
    int i = blk*256 + tid;                  // float4 index, 131072 total
    int o = i >> 8;                         // sp_w is [512 o][1024 k]
    int k = (i & 255) * 4;
    f32x4 v = *((const f32x4*)spw + i);
    uint2 ov; ov.x = cvt2(v.x, v.y); ov.y = cvt2(v.z, v.w);
    *(uint2*)(spwb + (size_t)(k>>3)*4096 + o*8 + (k&7)) = ov;
  } else if(blk < 768){
    if(blk == 512){   // zero BN accumulators (sstats 1024 + dstats 256) every launch
      for(int j = tid; j < 1280; j += 256) stats[j] = 0.f;
    }
    int i = (blk-512)*256 + tid;            // 65536 = o*512 + kc
    int o = i >> 9, kc = i & 511;
    int c = kc & 255, hi = kc >> 8;
    const float* w = ctw + ((size_t)c*128 + o)*4;   // [in 256][out 128][1][4]
    int j = ((kc>>3)<<10) + (o<<3) + (kc&7);
    Aev[j] = f2b1(w[hi ? 3 : 1]);           // A_even = [kw1 ; kw3]
    Aod[j] = f2b1(w[hi ? 2 : 0]);           // A_odd  = [kw0 ; kw2]
  } else {
    int blk2 = blk - 768;                   // 256 blocks: b(32) x cchunk(8)
    int b = blk2 >> 3, c0 = (blk2 & 7) * 128;
    const float* src = sf + (size_t)b*32768 + (size_t)c0*32;   // [c][32 m]
    #pragma unroll
    for(int it=0; it<4; ++it){
      int q = it*256 + tid;        // float4 id, 1024 total
      int c = q >> 3, m = (q & 7)*4;
      f32x4 v = *(const f32x4*)(src + c*32 + m);
      Ls[c*33+m] = v.x; Ls[c*33+m+1] = v.y; Ls[c*33+m+2] = v.z; Ls[c*33+m+3] = v.w;
    }
    // in-block kNN for this b (every spiT block recomputes; tiny, L2-cached)
    {
      int n = tid & 63;
      int t = b*64 + n;
      float v[32]; float sb = 0.f;
      const float* br = bef + (size_t)t * 32;
      #pragma unroll
      for(int c=0;c<32;c++){ float x = br[c]; v[c] = x; sb += x*x; }
      float d0 = 1e30f, d1 = 1e30f; int i0 = 0, i1 = 0;
      const float* cr = coor + (size_t)b * 1024;
      for(int m=0;m<32;m++){
        float dot = 0.f, sc = 0.f;
        #pragma unroll
        for(int c=0;c<32;c++){ float x = cr[m*32+c]; dot += v[c]*x; sc += x*x; }
        float d = sb + sc - 2.f*dot;
        if(d < d0){ d1 = d0; i1 = i0; d0 = d; i0 = m; }   // strict < keeps lowest idx on ties
        else if(d < d1){ d1 = d; i1 = m; }
      }
      float r0 = 1.f/(d0 + 1e-8f), r1 = 1.f/(d1 + 1e-8f);
      float sum = r0 + r1;
      if(tid < 64){
        ki0[n] = i0; ki1[n] = i1;
        kw0[n] = r0/sum; kw1[n] = r1/sum;
        if(c0 == 0){   // publish for k_mid / k_dout
          idx[t*2] = i0; idx[t*2+1] = i1;
          wgt[t*2] = r0/sum; wgt[t*2+1] = r1/sum;
        }
      }
    }
    __syncthreads();
    int n = tid & 63, ob = tid >> 6;
    int i0 = ki0[n], i1 = ki1[n];
    float w0 = kw0[n], w1 = kw1[n];
    ushort* dst = spiT + (size_t)b*65536 + n*8;
    #pragma unroll
    for(int it=0; it<4; ++it){
      int oct = ob + it*4;                 // 0..15 (8 c's each)
      float f[8];
      #pragma unroll
      for(int j=0;j<8;j++){
        int c = oct*8 + j;
        f[j] = w0*Ls[c*33+i0] + w1*Ls[c*33+i1];
      }
      uint4 uv; uv.x = cvt2(f[0],f[1]); uv.y = cvt2(f[2],f[3]);
      uv.z = cvt2(f[4],f[5]); uv.w = cvt2(f[6],f[7]);
      *(uint4*)(dst + (size_t)((c0>>3) + oct)*512) = uv;   // 64-lane contiguous 1KB store
    }
  }
}

// ---------------- K2: sgemm (blocks 0..511) || conv (blocks 512..1535) --------
// conv wave roles: wave = (parity pe, o-half oh). Each wave owns 64 o's and BOTH
// t-tiles -> each A-fragment feeds 2 MFMAs; block A-traffic = 256 KB (0 redundancy).
__global__ __launch_bounds__(256) void k_main(
    const ushort* __restrict__ spw, const ushort* __restrict__ spiT,
    const float* __restrict__ spb, float* __restrict__ h, float* __restrict__ sstats,
    const float* __restrict__ df, const ushort* __restrict__ Aev,
    const ushort* __restrict__ Aod, const float* __restrict__ ctb,
    ushort* __restrict__ z){
  __shared__ ushort L[66*256];   // 33792 B (conv path only)
  int tid = threadIdx.x;
  int wave = tid >> 6, lane = tid & 63;

  if(blockIdx.x < 512){
    // ================= sgemm =================
    int blk = blockIdx.x;
    int b = blk >> 4, og = (blk >> 1) & 7, nh = blk & 1;
    int lo = lane & 15, hi = lane >> 4;
    int o0 = og*64 + wave*16;
    const short* A = (const short*)spw  + (size_t)hi*4096 + (o0 + lo)*8;
    const short* B = (const short*)spiT + (size_t)b*65536 + (size_t)hi*512 + (nh*32 + lo)*8;
    f32x4 acc[2] = {};
    for(int kb = 0; kb < 128; kb += 4){
      short8 a = *(const short8*)(A + (size_t)kb*4096);
      acc[0] = MFMA16(a, *(const short8*)(B + (size_t)kb*512),       acc[0]);
      acc[1] = MFMA16(a, *(const short8*)(B + (size_t)kb*512 + 128), acc[1]);
    }
    float sv[4], sv2[4], bias[4];
    #pragma unroll
    for(int r=0;r<4;r++){ sv[r]=0.f; sv2[r]=0.f; bias[r] = spb[o0 + hi*4 + r]; }
    #pragma unroll
    for(int q=0;q<2;q++){
      int n = nh*32 + q*16 + lo;
      #pragma unroll
      for(int r=0;r<4;r++){
        int o = o0 + hi*4 + r;
        float val = acc[q][r] + bias[r];
        h[(size_t)o*2048 + b*64 + n] = val;
        sv[r] += val; sv2[r] += val*val;
      }
    }
    #pragma unroll
    for(int r=0;r<4;r++){
      #pragma unroll
      for(int off=1; off<16; off<<=1){
        sv[r]  += __shfl_xor(sv[r],  off);
        sv2[r] += __shfl_xor(sv2[r], off);
      }
    }
    if(lo == 0){
      #pragma unroll
      for(int r=0;r<4;r++){
        int o = o0 + hi*4 + r;
        atomicAdd(&sstats[o*2],   sv[r]);
        atomicAdd(&sstats[o*2+1], sv2[r]);
      }
    }
    return;
  }

  // ================= conv =================
  int bs_ = blockIdx.x - 512; int b = bs_ >> 5, s = bs_ & 31;
  { // zero boundary rows 0 and 65
    unsigned* Lw = (unsigned*)L;
    int i = (tid < 128) ? tid : (65*128 + (tid - 128));
    Lw[i] = 0u;
  }
  // stage + transpose + f32->bf16: thread = p (64 lanes), c-oct; 8 iters.
  {
    int p = tid & 63;
    const float* src = df + ((size_t)(b*256)*32 + s)*64 + p;   // + c*2048
    int row = p + 1;
    char* Lrow = (char*)L + row*512;
    int rsw = row & 31;
    #pragma unroll
    for(int it=0; it<8; ++it){
      int oct = (tid >> 6) + it*4;        // 0..31
      const float* sc = src + (size_t)oct*8*2048;
      float f[8];
      #pragma unroll
      for(int j=0;j<8;j++) f[j] = sc[(size_t)j*2048];
      uint4 uv; uv.x = cvt2(f[0],f[1]); uv.y = cvt2(f[2],f[3]);
      uv.z = cvt2(f[4],f[5]); uv.w = cvt2(f[6],f[7]);
      *(uint4*)(Lrow + ((oct ^ rsw) << 4)) = uv;
    }
  }
  __syncthreads();

  int pe = wave >> 1, oh = wave & 1;     // parity, o-half
  int tcol = lane & 31;
  int kl = (lane >> 5) * 8;              // k sub-group for LDS B-frag
  const short* A = (const short*)(pe ? Aod : Aev)
                   + (size_t)(lane>>5)*1024 + (oh*64 + tcol)*8;
  f32x16 acc[2][2] = {};                 // [t-tile tt][o-tile ot]
  #pragma unroll
  for(int hf=0; hf<2; ++hf){
    int r0 = tcol + (hf==0 ? 1 : 0) + pe;      // tt=0 source row; tt=1 is r0+32
    int rsw = r0 & 31;                          // (r0+32)&31 == r0&31
    const char* Lr0 = (const char*)L + r0*512;
    const char* Lr1 = (const char*)L + (r0+32)*512;
    for(int k0=0; k0<256; k0+=16){
      int sidx = (k0 + kl) >> 3;               // LDS slot (column oct)
      int so = (sidx ^ rsw) << 4;
      short8 b0 = *(const short8*)(Lr0 + so);
      short8 b1 = *(const short8*)(Lr1 + so);
      const short* Ab = A + (size_t)((hf*256 + k0) >> 3)*1024;
      #pragma unroll
      for(int ot=0; ot<2; ++ot){
        short8 afrag = *(const short8*)(Ab + ot*256);   // one A-frag, two MFMAs
        acc[0][ot] = MFMA32(afrag, b0, acc[0][ot]);
        acc[1][ot] = MFMA32(afrag, b1, acc[1][ot]);
      }
    }
  }
  __syncthreads();   // all waves done reading L before repack overwrite

  // repack via LDS: Z[o 128][wo 128] bf16 (32 KB, reuse L)
  #pragma unroll
  for(int tt=0; tt<2; ++tt){
    #pragma unroll
    for(int ot=0; ot<2; ++ot){
      #pragma unroll
      for(int r=0;r<16;r++){
        int o = oh*64 + ot*32 + (r&3) + 8*(r>>2) + 4*(lane>>5);
        L[o*128 + 2*(tt*32 + tcol) + pe] = f2b1(acc[tt][ot][r] + ctb[o]);
      }
    }
  }
  __syncthreads();
  // linear coalesced store: z[b][o][s][wo]
  ushort* zb = z + ((size_t)(b*128)*32 + s)*128;
  #pragma unroll
  for(int it=0; it<8; ++it){
    int q = it*256 + tid;          // short8 chunk, 2048 total
    int o = q >> 4, w0 = (q & 15)*8;
    *(short8*)(zb + (size_t)o*4096 + w0) = *(const short8*)(L + o*128 + w0);
  }
}

// ---------------- K3: merged sparse-BN normalize + dense-BN stats -------------
// blocks [0,512): sbn (o = blk); blocks [512, 4608): dstats task = blk-512
__global__ __launch_bounds__(256) void k_mid(const float* __restrict__ h,
    const float* __restrict__ sstats, const float* __restrict__ gam,
    const float* __restrict__ bet, float* __restrict__ out,
    const ushort* __restrict__ z, const int* __restrict__ idx,
    const float* __restrict__ wgt, float* __restrict__ dstats){
  __shared__ float ps[4], ps2[4];
  __shared__ uint4 Lz[512];              // 8 KB z slab
  int blk = blockIdx.x, tid = threadIdx.x;
  if(blk < 512){
    int o = blk;
    float mu = sstats[o*2] / 2048.f;
    float var = fmaxf(sstats[o*2+1] / 2048.f - mu*mu, 0.f);
    float a = gam[o] * rsqrtf(var + 1e-5f);
    float be = bet[o];
    const float* row = h + (size_t)o * 2048;
    #pragma unroll
    for(int it=0; it<2; ++it){
      int j = it*1024 + tid*4;
      f32x4 v = *(const f32x4*)(row + j);
      f32x4 r;
      r.x = relu(a*(v.x-mu)+be); r.y = relu(a*(v.y-mu)+be);
      r.z = relu(a*(v.z-mu)+be); r.w = relu(a*(v.w-mu)+be);
      int b = j >> 6, n = j & 63;
      *(f32x4*)(out + ((size_t)b*512 + o)*64 + n) = r;
    }
  } else {
    int t = blk - 512; int b = t >> 7, o = t & 127;
    const uint4* zq = (const uint4*)(z + (size_t)(b*128 + o) * 4096);  // [32 s][16 chunks]
    Lz[tid]       = zq[tid];
    Lz[tid + 256] = zq[tid + 256];
    __syncthreads();
    int wq = tid & 15, ng = tid >> 4;       // 16 chunks x 16 n-groups
    float s = 0.f, s2 = 0.f;
    for(int n = ng; n < 64; n += 16){
      int bn = b*64 + n;
      float w0 = wgt[bn*2], w1 = wgt[bn*2+1];
      int i0 = idx[bn*2], i1 = idx[bn*2+1];
      uint4 a0 = Lz[i0*16 + wq], a1 = Lz[i1*16 + wq];
      #pragma unroll
      for(int j=0;j<4;j++){
        unsigned u0 = (&a0.x)[j], u1 = (&a1.x)[j];
        float y0 = w0*b2f((ushort)u0)       + w1*b2f((ushort)u1);
        float y1 = w0*b2f((ushort)(u0>>16)) + w1*b2f((ushort)(u1>>16));
        s += y0 + y1; s2 += y0*y0 + y1*y1;
      }
    }
    #pragma unroll
    for(int off=32; off; off>>=1){ s += __shfl_down(s, off); s2 += __shfl_down(s2, off); }
    int wave = tid >> 6, lane = tid & 63;
    if(lane == 0){ ps[wave] = s; ps2[wave] = s2; }
    __syncthreads();
    if(tid == 0){
      atomicAdd(&dstats[o*2],   ps[0]+ps[1]+ps[2]+ps[3]);
      atomicAdd(&dstats[o*2+1], ps2[0]+ps2[1]+ps2[2]+ps2[3]);
    }
  }
}

// ---------------- K4: dense normalize + ReLU -> d_out (LDS-staged gather) -----
__global__ __launch_bounds__(256) void k_dout(const ushort* __restrict__ z,
    const int* __restrict__ idx, const float* __restrict__ wgt,
    const float* __restrict__ stats, const float* __restrict__ gam,
    const float* __restrict__ bet, float* __restrict__ out){
  __shared__ uint4 Lz[512];              // 8 KB z slab
  int blk = blockIdx.x; int b = blk >> 7, o = blk & 127;
  const float N = 262144.f;
  float mu = stats[o*2] / N;
  float var = fmaxf(stats[o*2+1] / N - mu*mu, 0.f);
  float a = gam[o] * rsqrtf(var + 1e-5f);
  float be = bet[o];
  int tid = threadIdx.x;
  const uint4* zq = (const uint4*)(z + (size_t)(b*128 + o) * 4096);
  Lz[tid]       = zq[tid];
  Lz[tid + 256] = zq[tid + 256];
  __syncthreads();
  float* ob = out + 1048576 + (size_t)(b*128 + o) * 8192;   // [n 64][wo 128]
  int wq = tid & 15, ng = tid >> 4;
  for(int n = ng; n < 64; n += 16){
    int bn = b*64 + n;
    float w0 = wgt[bn*2], w1 = wgt[bn*2+1];
    int i0 = idx[bn*2], i1 = idx[bn*2+1];
    uint4 a0 = Lz[i0*16 + wq], a1 = Lz[i1*16 + wq];
    float y[8];
    #pragma unroll
    for(int j=0;j<4;j++){
      unsigned u0 = (&a0.x)[j], u1 = (&a1.x)[j];
      y[2*j]   = w0*b2f((ushort)u0)       + w1*b2f((ushort)u1);
      y[2*j+1] = w0*b2f((ushort)(u0>>16)) + w1*b2f((ushort)(u1>>16));
    }
    f32x4 r0, r1;
    r0.x = relu(a*(y[0]-mu)+be); r0.y = relu(a*(y[1]-mu)+be);
    r0.z = relu(a*(y[2]-mu)+be); r0.w = relu(a*(y[3]-mu)+be);
    r1.x = relu(a*(y[4]-mu)+be); r1.y = relu(a*(y[5]-mu)+be);
    r1.z = relu(a*(y[6]-mu)+be); r1.w = relu(a*(y[7]-mu)+be);
    *(f32x4*)(ob + n*128 + wq*8)     = r0;
    *(f32x4*)(ob + n*128 + wq*8 + 4) = r1;
  }
}

extern "C" void kernel_launch(void* const* d_in, const int* in_sizes, int n_in,
                              void* d_out, int out_size, void* d_ws, size_t ws_size,
                              hipStream_t stream) {
  (void)in_sizes; (void)n_in; (void)out_size; (void)ws_size;
  const float* sparse_fea = (const float*)d_in[0];
  const float* dense_fea  = (const float*)d_in[1];
  const float* stk_coor   = (const float*)d_in[2];
  const float* stk_bef    = (const float*)d_in[3];
  const float* sp_w   = (const float*)d_in[4];
  const float* sp_b   = (const float*)d_in[5];
  const float* sp_g   = (const float*)d_in[6];
  const float* sp_be  = (const float*)d_in[7];
  const float* ct_w   = (const float*)d_in[8];
  const float* ct_b   = (const float*)d_in[9];
  const float* bn_g   = (const float*)d_in[10];
  const float* bn_be  = (const float*)d_in[11];
  float* out = (float*)d_out;

  char* ws = (char*)d_ws;
  int*    idx    = (int*)   (ws + 0);          //  16 KB
  float*  wgt    = (float*) (ws + 16384);      //  16 KB
  float*  sstats = (float*) (ws + 32768);      //   4 KB (512 o x {sum,sumsq})
  float*  dstats = (float*) (ws + 36864);      //   1 KB (contiguous after sstats)
  ushort* Aev    = (ushort*)(ws + 40960);      // 128 KB (panel)
  ushort* Aod    = (ushort*)(ws + 172032);     // 128 KB (panel)
  ushort* spwb   = (ushort*)(ws + 303104);     //   1 MB (sp_w bf16 panel)
  ushort* spiT   = (ushort*)(ws + 1351680);    //   4 MB (panel)
  float*  h      = (float*) (ws + 5545984);    //   4 MB
  ushort* z      = (ushort*)(ws + 9740288);    //  32 MB

  hipLaunchKernelGGL(k_prep, dim3(1024), dim3(256), 0, stream,
                     sp_w, spwb, ct_w, Aev, Aod, sparse_fea, stk_bef, stk_coor,
                     idx, wgt, spiT, sstats);
  hipLaunchKernelGGL(k_main, dim3(1536), dim3(256), 0, stream,
                     spwb, spiT, sp_b, h, sstats, dense_fea, Aev, Aod, ct_b, z);
  hipLaunchKernelGGL(k_mid,  dim3(4608), dim3(256), 0, stream,
                     h, sstats, sp_g, sp_be, out, z, idx, wgt, dstats);
  hipLaunchKernelGGL(k_dout, dim3(4096), dim3(256), 0, stream,
                     z, idx, wgt, dstats, bn_g, bn_be, out);
}

// Round 15
// 131.568 us; speedup vs baseline: 1.7022x; 1.2538x over previous
//
#include <hip/hip_runtime.h>
#include <hip/hip_bf16.h>

typedef __attribute__((ext_vector_type(8))) short short8;
typedef __attribute__((ext_vector_type(4))) float f32x4;
typedef __attribute__((ext_vector_type(16))) float f32x16;

#define MFMA16(a,b,c) __builtin_amdgcn_mfma_f32_16x16x32_bf16((a),(b),(c),0,0,0)
#define MFMA32(a,b,c) __builtin_amdgcn_mfma_f32_32x32x16_bf16((a),(b),(c),0,0,0)

static __device__ __forceinline__ float b2f(ushort u){
  union { unsigned u32; float f; } x; x.u32 = ((unsigned)u) << 16; return x.f;
}
// packed f32->bf16 (RNE), 1 VALU for 2 values
static __device__ __forceinline__ unsigned cvt2(float lo, float hi){
  unsigned r; asm("v_cvt_pk_bf16_f32 %0, %1, %2" : "=v"(r) : "v"(lo), "v"(hi)); return r;
}
static __device__ __forceinline__ ushort f2b1(float f){
  unsigned r; asm("v_cvt_pk_bf16_f32 %0, %1, %2" : "=v"(r) : "v"(f), "v"(f));
  return (ushort)r;
}
// NaN-PROPAGATING relu (fmaxf(NaN,0)==0 would mask upstream NaNs)
static __device__ __forceinline__ float relu(float v){ return (v <= 0.f) ? 0.f : v; }

// ---------------- K1: prep panels + in-block kNN + sparse interp (1024 blocks)
__global__ __launch_bounds__(256) void k_prep(
    const float* __restrict__ spw, ushort* __restrict__ spwb,
    const float* __restrict__ ctw, ushort* __restrict__ Aev, ushort* __restrict__ Aod,
    const float* __restrict__ sf, const float* __restrict__ bef,
    const float* __restrict__ coor, int* __restrict__ idx, float* __restrict__ wgt,
    ushort* __restrict__ spiT, float* __restrict__ stats){
  __shared__ float Ls[128*33];
  __shared__ float kw0[64], kw1[64];
  __shared__ int   ki0[64], ki1[64];
  int blk = blockIdx.x, tid = threadIdx.x;
  if(blk < 512){
    int i = blk*256 + tid;                  // float4 index, 131072 total
    int o = i >> 8;                         // sp_w is [512 o][1024 k]
    int k = (i & 255) * 4;
    f32x4 v = *((const f32x4*)spw + i);
    uint2 ov; ov.x = cvt2(v.x, v.y); ov.y = cvt2(v.z, v.w);
    *(uint2*)(spwb + (size_t)(k>>3)*4096 + o*8 + (k&7)) = ov;
  } else if(blk < 768){
    if(blk == 512){   // zero BN accumulators (sstats 1024 + dstats 256) every launch
      for(int j = tid; j < 1280; j += 256) stats[j] = 0.f;
    }
    int i = (blk-512)*256 + tid;            // 65536 = o*512 + kc
    int o = i >> 9, kc = i & 511;
    int c = kc & 255, hi = kc >> 8;
    const float* w = ctw + ((size_t)c*128 + o)*4;   // [in 256][out 128][1][4]
    int j = ((kc>>3)<<10) + (o<<3) + (kc&7);
    Aev[j] = f2b1(w[hi ? 3 : 1]);           // A_even = [kw1 ; kw3]
    Aod[j] = f2b1(w[hi ? 2 : 0]);           // A_odd  = [kw0 ; kw2]
  } else {
    int blk2 = blk - 768;                   // 256 blocks: b(32) x cchunk(8)
    int b = blk2 >> 3, c0 = (blk2 & 7) * 128;
    const float* src = sf + (size_t)b*32768 + (size_t)c0*32;   // [c][32 m]
    #pragma unroll
    for(int it=0; it<4; ++it){
      int q = it*256 + tid;        // float4 id, 1024 total
      int c = q >> 3, m = (q & 7)*4;
      f32x4 v = *(const f32x4*)(src + c*32 + m);
      Ls[c*33+m] = v.x; Ls[c*33+m+1] = v.y; Ls[c*33+m+2] = v.z; Ls[c*33+m+3] = v.w;
    }
    // in-block kNN for this b (every spiT block recomputes; tiny, L2-cached)
    {
      int n = tid & 63;
      int t = b*64 + n;
      float v[32]; float sb = 0.f;
      const float* br = bef + (size_t)t * 32;
      #pragma unroll
      for(int c=0;c<32;c++){ float x = br[c]; v[c] = x; sb += x*x; }
      float d0 = 1e30f, d1 = 1e30f; int i0 = 0, i1 = 0;
      const float* cr = coor + (size_t)b * 1024;
      for(int m=0;m<32;m++){
        float dot = 0.f, sc = 0.f;
        #pragma unroll
        for(int c=0;c<32;c++){ float x = cr[m*32+c]; dot += v[c]*x; sc += x*x; }
        float d = sb + sc - 2.f*dot;
        if(d < d0){ d1 = d0; i1 = i0; d0 = d; i0 = m; }   // strict < keeps lowest idx on ties
        else if(d < d1){ d1 = d; i1 = m; }
      }
      float r0 = 1.f/(d0 + 1e-8f), r1 = 1.f/(d1 + 1e-8f);
      float sum = r0 + r1;
      if(tid < 64){
        ki0[n] = i0; ki1[n] = i1;
        kw0[n] = r0/sum; kw1[n] = r1/sum;
        if(c0 == 0){   // publish for k_mid / k_dout
          idx[t*2] = i0; idx[t*2+1] = i1;
          wgt[t*2] = r0/sum; wgt[t*2+1] = r1/sum;
        }
      }
    }
    __syncthreads();
    int n = tid & 63, ob = tid >> 6;
    int i0 = ki0[n], i1 = ki1[n];
    float w0 = kw0[n], w1 = kw1[n];
    ushort* dst = spiT + (size_t)b*65536 + n*8;
    #pragma unroll
    for(int it=0; it<4; ++it){
      int oct = ob + it*4;                 // 0..15 (8 c's each)
      float f[8];
      #pragma unroll
      for(int j=0;j<8;j++){
        int c = oct*8 + j;
        f[j] = w0*Ls[c*33+i0] + w1*Ls[c*33+i1];
      }
      uint4 uv; uv.x = cvt2(f[0],f[1]); uv.y = cvt2(f[2],f[3]);
      uv.z = cvt2(f[4],f[5]); uv.w = cvt2(f[6],f[7]);
      *(uint4*)(dst + (size_t)((c0>>3) + oct)*512) = uv;   // 64-lane contiguous 1KB store
    }
  }
}

// ---------------- K2: sgemm (blocks 0..511) || conv (blocks 512..1535) --------
// VGPR capped at 128 (4 waves/EU) so the LDS-limited 4 blocks/CU is preserved
// while the float4 staging loads get register headroom to stay in flight.
__global__ __launch_bounds__(256, 4) void k_main(
    const ushort* __restrict__ spw, const ushort* __restrict__ spiT,
    const float* __restrict__ spb, float* __restrict__ h, float* __restrict__ sstats,
    const float* __restrict__ df, const ushort* __restrict__ Aev,
    const ushort* __restrict__ Aod, const float* __restrict__ ctb,
    ushort* __restrict__ z){
  __shared__ ushort L[66*256];   // 33792 B (conv path only)
  int tid = threadIdx.x;
  int wave = tid >> 6, lane = tid & 63;

  if(blockIdx.x < 512){
    // ================= sgemm =================
    int blk = blockIdx.x;
    int b = blk >> 4, og = (blk >> 1) & 7, nh = blk & 1;
    int lo = lane & 15, hi = lane >> 4;
    int o0 = og*64 + wave*16;
    const short* A = (const short*)spw  + (size_t)hi*4096 + (o0 + lo)*8;
    const short* B = (const short*)spiT + (size_t)b*65536 + (size_t)hi*512 + (nh*32 + lo)*8;
    f32x4 acc[2] = {};
    for(int kb = 0; kb < 128; kb += 4){
      short8 a = *(const short8*)(A + (size_t)kb*4096);
      acc[0] = MFMA16(a, *(const short8*)(B + (size_t)kb*512),       acc[0]);
      acc[1] = MFMA16(a, *(const short8*)(B + (size_t)kb*512 + 128), acc[1]);
    }
    float sv[4], sv2[4], bias[4];
    #pragma unroll
    for(int r=0;r<4;r++){ sv[r]=0.f; sv2[r]=0.f; bias[r] = spb[o0 + hi*4 + r]; }
    #pragma unroll
    for(int q=0;q<2;q++){
      int n = nh*32 + q*16 + lo;
      #pragma unroll
      for(int r=0;r<4;r++){
        int o = o0 + hi*4 + r;
        float val = acc[q][r] + bias[r];
        h[(size_t)o*2048 + b*64 + n] = val;
        sv[r] += val; sv2[r] += val*val;
      }
    }
    #pragma unroll
    for(int r=0;r<4;r++){
      #pragma unroll
      for(int off=1; off<16; off<<=1){
        sv[r]  += __shfl_xor(sv[r],  off);
        sv2[r] += __shfl_xor(sv2[r], off);
      }
    }
    if(lo == 0){
      #pragma unroll
      for(int r=0;r<4;r++){
        int o = o0 + hi*4 + r;
        atomicAdd(&sstats[o*2],   sv[r]);
        atomicAdd(&sstats[o*2+1], sv2[r]);
      }
    }
    return;
  }

  // ================= conv =================
  int bs_ = blockIdx.x - 512; int b = bs_ >> 5, s = bs_ & 31;
  { // zero boundary rows 0 and 65
    unsigned* Lw = (unsigned*)L;
    int i = (tid < 128) ? tid : (65*128 + (tid - 128));
    Lw[i] = 0u;
  }
  // stage + transpose + f32->bf16: FLOAT4 along p (1 KB/wave-instr, 16 loads/thread),
  // scattered ds_write_b16 into the SAME slot-XOR layout as before:
  //   byte = row*512 + (((c>>3) ^ (row&31)) << 4) + 2*(c&7)
  {
    const float* src = df + ((size_t)(b*256)*32 + s)*64;   // + c*2048 + p
    int q = tid & 15, cl = tid >> 4;       // p-quad, c-local
    #pragma unroll
    for(int it=0; it<16; ++it){
      int c = it*16 + cl;
      f32x4 v = *(const f32x4*)(src + (size_t)c*2048 + q*4);
      int cb = 2*(c & 7), cs = c >> 3;
      #pragma unroll
      for(int j=0;j<4;j++){
        int row = q*4 + j + 1;
        float fv = (j==0)?v.x:(j==1)?v.y:(j==2)?v.z:v.w;
        *(ushort*)((char*)L + row*512 + (((cs ^ (row & 31)) << 4) + cb)) = f2b1(fv);
      }
    }
  }
  __syncthreads();

  int pe = wave >> 1, tt = wave & 1;     // parity, t-tile
  int tcol = lane & 31;
  int t = tt*32 + tcol;
  int kl = (lane >> 5) * 8;              // k sub-group for LDS B-frag
  const short* A = (const short*)(pe ? Aod : Aev) + (size_t)(lane>>5)*1024 + tcol*8;
  f32x16 acc[4] = {};
  #pragma unroll
  for(int hf=0; hf<2; ++hf){
    int rowr = t + (hf==0 ? 1 : 0) + pe;       // source L-row for this parity/half
    const char* Lr = (const char*)L + rowr*512;
    int rsw = rowr & 31;
    for(int k0=0; k0<256; k0+=16){
      int sidx = (k0 + kl) >> 3;               // LDS slot (column oct)
      short8 bfrag = *(const short8*)(Lr + ((sidx ^ rsw) << 4));
      const short* Ab = A + (size_t)((hf*256 + k0) >> 3)*1024;
      #pragma unroll
      for(int ot=0; ot<4; ++ot){
        short8 afrag = *(const short8*)(Ab + ot*256);   // 2x512B contiguous segments
        acc[ot] = MFMA32(afrag, bfrag, acc[ot]);
      }
    }
  }
  __syncthreads();   // all waves done reading L before repack overwrite

  // repack via LDS: Z[o 128][wo 128] bf16 (32 KB, reuse L)
  #pragma unroll
  for(int ot=0; ot<4; ++ot){
    #pragma unroll
    for(int r=0;r<16;r++){
      int o = ot*32 + (r&3) + 8*(r>>2) + 4*(lane>>5);
      L[o*128 + 2*t + pe] = f2b1(acc[ot][r] + ctb[o]);
    }
  }
  __syncthreads();
  // linear coalesced store: z[b][o][s][wo]
  ushort* zb = z + ((size_t)(b*128)*32 + s)*128;
  #pragma unroll
  for(int it=0; it<8; ++it){
    int q = it*256 + tid;          // short8 chunk, 2048 total
    int o = q >> 4, w0 = (q & 15)*8;
    *(short8*)(zb + (size_t)o*4096 + w0) = *(const short8*)(L + o*128 + w0);
  }
}

// ---------------- K3: merged sparse-BN normalize + dense-BN stats -------------
__global__ __launch_bounds__(256) void k_mid(const float* __restrict__ h,
    const float* __restrict__ sstats, const float* __restrict__ gam,
    const float* __restrict__ bet, float* __restrict__ out,
    const ushort* __restrict__ z, const int* __restrict__ idx,
    const float* __restrict__ wgt, float* __restrict__ dstats){
  __shared__ float ps[4], ps2[4];
  __shared__ uint4 Lz[512];              // 8 KB z slab
  int blk = blockIdx.x, tid = threadIdx.x;
  if(blk < 512){
    int o = blk;
    float mu = sstats[o*2] / 2048.f;
    float var = fmaxf(sstats[o*2+1] / 2048.f - mu*mu, 0.f);
    float a = gam[o] * rsqrtf(var + 1e-5f);
    float be = bet[o];
    const float* row = h + (size_t)o * 2048;
    #pragma unroll
    for(int it=0; it<2; ++it){
      int j = it*1024 + tid*4;
      f32x4 v = *(const f32x4*)(row + j);
      f32x4 r;
      r.x = relu(a*(v.x-mu)+be); r.y = relu(a*(v.y-mu)+be);
      r.z = relu(a*(v.z-mu)+be); r.w = relu(a*(v.w-mu)+be);
      int b = j >> 6, n = j & 63;
      *(f32x4*)(out + ((size_t)b*512 + o)*64 + n) = r;
    }
  } else {
    int t = blk - 512; int b = t >> 7, o = t & 127;
    const uint4* zq = (const uint4*)(z + (size_t)(b*128 + o) * 4096);  // [32 s][16 chunks]
    Lz[tid]       = zq[tid];
    Lz[tid + 256] = zq[tid + 256];
    __syncthreads();
    int wq = tid & 15, ng = tid >> 4;       // 16 chunks x 16 n-groups
    float s = 0.f, s2 = 0.f;
    for(int n = ng; n < 64; n += 16){
      int bn = b*64 + n;
      float w0 = wgt[bn*2], w1 = wgt[bn*2+1];
      int i0 = idx[bn*2], i1 = idx[bn*2+1];
      uint4 a0 = Lz[i0*16 + wq], a1 = Lz[i1*16 + wq];
      #pragma unroll
      for(int j=0;j<4;j++){
        unsigned u0 = (&a0.x)[j], u1 = (&a1.x)[j];
        float y0 = w0*b2f((ushort)u0)       + w1*b2f((ushort)u1);
        float y1 = w0*b2f((ushort)(u0>>16)) + w1*b2f((ushort)(u1>>16));
        s += y0 + y1; s2 += y0*y0 + y1*y1;
      }
    }
    #pragma unroll
    for(int off=32; off; off>>=1){ s += __shfl_down(s, off); s2 += __shfl_down(s2, off); }
    int wave = tid >> 6, lane = tid & 63;
    if(lane == 0){ ps[wave] = s; ps2[wave] = s2; }
    __syncthreads();
    if(tid == 0){
      atomicAdd(&dstats[o*2],   ps[0]+ps[1]+ps[2]+ps[3]);
      atomicAdd(&dstats[o*2+1], ps2[0]+ps2[1]+ps2[2]+ps2[3]);
    }
  }
}

// ---------------- K4: dense normalize + ReLU -> d_out (LDS-staged gather) -----
__global__ __launch_bounds__(256) void k_dout(const ushort* __restrict__ z,
    const int* __restrict__ idx, const float* __restrict__ wgt,
    const float* __restrict__ stats, const float* __restrict__ gam,
    const float* __restrict__ bet, float* __restrict__ out){
  __shared__ uint4 Lz[512];              // 8 KB z slab
  int blk = blockIdx.x; int b = blk >> 7, o = blk & 127;
  const float N = 262144.f;
  float mu = stats[o*2] / N;
  float var = fmaxf(stats[o*2+1] / N - mu*mu, 0.f);
  float a = gam[o] * rsqrtf(var + 1e-5f);
  float be = bet[o];
  int tid = threadIdx.x;
  const uint4* zq = (const uint4*)(z + (size_t)(b*128 + o) * 4096);
  Lz[tid]       = zq[tid];
  Lz[tid + 256] = zq[tid + 256];
  __syncthreads();
  float* ob = out + 1048576 + (size_t)(b*128 + o) * 8192;   // [n 64][wo 128]
  int wq = tid & 15, ng = tid >> 4;
  for(int n = ng; n < 64; n += 16){
    int bn = b*64 + n;
    float w0 = wgt[bn*2], w1 = wgt[bn*2+1];
    int i0 = idx[bn*2], i1 = idx[bn*2+1];
    uint4 a0 = Lz[i0*16 + wq], a1 = Lz[i1*16 + wq];
    float y[8];
    #pragma unroll
    for(int j=0;j<4;j++){
      unsigned u0 = (&a0.x)[j], u1 = (&a1.x)[j];
      y[2*j]   = w0*b2f((ushort)u0)       + w1*b2f((ushort)u1);
      y[2*j+1] = w0*b2f((ushort)(u0>>16)) + w1*b2f((ushort)(u1>>16));
    }
    f32x4 r0, r1;
    r0.x = relu(a*(y[0]-mu)+be); r0.y = relu(a*(y[1]-mu)+be);
    r0.z = relu(a*(y[2]-mu)+be); r0.w = relu(a*(y[3]-mu)+be);
    r1.x = relu(a*(y[4]-mu)+be); r1.y = relu(a*(y[5]-mu)+be);
    r1.z = relu(a*(y[6]-mu)+be); r1.w = relu(a*(y[7]-mu)+be);
    *(f32x4*)(ob + n*128 + wq*8)     = r0;
    *(f32x4*)(ob + n*128 + wq*8 + 4) = r1;
  }
}

extern "C" void kernel_launch(void* const* d_in, const int* in_sizes, int n_in,
                              void* d_out, int out_size, void* d_ws, size_t ws_size,
                              hipStream_t stream) {
  (void)in_sizes; (void)n_in; (void)out_size; (void)ws_size;
  const float* sparse_fea = (const float*)d_in[0];
  const float* dense_fea  = (const float*)d_in[1];
  const float* stk_coor   = (const float*)d_in[2];
  const float* stk_bef    = (const float*)d_in[3];
  const float* sp_w   = (const float*)d_in[4];
  const float* sp_b   = (const float*)d_in[5];
  const float* sp_g   = (const float*)d_in[6];
  const float* sp_be  = (const float*)d_in[7];
  const float* ct_w   = (const float*)d_in[8];
  const float* ct_b   = (const float*)d_in[9];
  const float* bn_g   = (const float*)d_in[10];
  const float* bn_be  = (const float*)d_in[11];
  float* out = (float*)d_out;

  char* ws = (char*)d_ws;
  int*    idx    = (int*)   (ws + 0);          //  16 KB
  float*  wgt    = (float*) (ws + 16384);      //  16 KB
  float*  sstats = (float*) (ws + 32768);      //   4 KB (512 o x {sum,sumsq})
  float*  dstats = (float*) (ws + 36864);      //   1 KB (contiguous after sstats)
  ushort* Aev    = (ushort*)(ws + 40960);      // 128 KB (panel)
  ushort* Aod    = (ushort*)(ws + 172032);     // 128 KB (panel)
  ushort* spwb   = (ushort*)(ws + 303104);     //   1 MB (sp_w bf16 panel)
  ushort* spiT   = (ushort*)(ws + 1351680);    //   4 MB (panel)
  float*  h      = (float*) (ws + 5545984);    //   4 MB
  ushort* z      = (ushort*)(ws + 9740288);    //  32 MB

  hipLaunchKernelGGL(k_prep, dim3(1024), dim3(256), 0, stream,
                     sp_w, spwb, ct_w, Aev, Aod, sparse_fea, stk_bef, stk_coor,
                     idx, wgt, spiT, sstats);
  hipLaunchKernelGGL(k_main, dim3(1536), dim3(256), 0, stream,
                     spwb, spiT, sp_b, h, sstats, dense_fea, Aev, Aod, ct_b, z);
  hipLaunchKernelGGL(k_mid,  dim3(4608), dim3(256), 0, stream,
                     h, sstats, sp_g, sp_be, out, z, idx, wgt, dstats);
  hipLaunchKernelGGL(k_dout, dim3(4096), dim3(256), 0, stream,
                     z, idx, wgt, dstats, bn_g, bn_be, out);
}